// Round 1
// baseline (239.730 us; speedup 1.0000x reference)
//
#include <hip/hip_runtime.h>

#define N_NODES   100000
#define N_FEAT    128
#define N_EDGES   1600000
#define HIDDEN    64
#define NUM_GRAPHS 64
#define CHUNK   8192
#define NCHUNK  ((N_EDGES + CHUNK - 1) / CHUNK)   // 196
#define BSHIFT  8
#define NBUCKET ((N_NODES + 255) >> 8)            // 391 buckets of 256 nodes
#define OFFS_W  (NBUCKET + 1)                     // 392 entries per chunk
#define CAP     4800                              // max bucket size (mean 4092 + 11 sigma)
#define WT_BLOCKS 4
#define GEMM_GRID ((N_NODES + 127) / 128)         // 782 blocks of 128 rows

typedef unsigned int  uint32;
typedef unsigned short ushort16;

typedef __attribute__((ext_vector_type(8))) __bf16 bf16x8;
typedef __attribute__((ext_vector_type(4))) float  f32x4;
union Frag8 { bf16x8 v; unsigned short s[8]; uint4 q; };

// fp32 -> bf16 round-to-nearest-even
static __device__ __forceinline__ unsigned short f2bf(float f) {
    uint32 u = __float_as_uint(f);
    u += 0x7fffu + ((u >> 16) & 1u);
    return (unsigned short)(u >> 16);
}

// ---------------------------------------------------------------------------
// L1: blocks [0,4)   : Wt[n][k] = bf16(W[k][n])   (independent of edges)
//     blocks [4,200) : partition edges into 391 dst-buckets per 8192-edge
//                      chunk via LDS; all global writes coalesced.
// The two jobs share no data; fusing them overlaps the tiny transpose under
// the partition and removes one launch.
// ---------------------------------------------------------------------------
__global__ __launch_bounds__(512) void k_pre(const float* __restrict__ W,
                                             ushort16* __restrict__ Wt,
                                             const int* __restrict__ ei,
                                             int* __restrict__ src_out,
                                             unsigned char* __restrict__ dst8,
                                             int* __restrict__ offs) {
    __shared__ int hist[512];
    __shared__ int excl[512];
    __shared__ int ssrc[CHUNK];     // 32 KB
    __shared__ int sdst[CHUNK];     // 32 KB

    if (blockIdx.x < WT_BLOCKS) {   // ---- w_transpose: 128*64 = 8192 elems
        const int base = blockIdx.x * 2048 + threadIdx.x;
#pragma unroll
        for (int j = 0; j < 4; ++j) {
            const int idx = base + j * 512;
            const int k = idx >> 6, n = idx & 63;
            Wt[n * N_FEAT + k] = f2bf(W[idx]);
        }
        return;
    }

    // ---- partition ----
    const int c = blockIdx.x - WT_BLOCKS;
    const int base = c * CHUNK;
    const int n = min(CHUNK, N_EDGES - base);   // always a multiple of 4
    const int t = threadIdx.x;
    hist[t] = 0;
    __syncthreads();

    int es[CHUNK / 512], ed[CHUNK / 512], rk[CHUNK / 512];
#pragma unroll
    for (int k = 0; k < CHUNK / 512; ++k) {
        const int i = t + k * 512;
        if (i < n) {
            ed[k] = __builtin_nontemporal_load(&ei[N_EDGES + base + i]);
            es[k] = __builtin_nontemporal_load(&ei[base + i]);
            rk[k] = atomicAdd(&hist[ed[k] >> BSHIFT], 1);
        }
    }
    __syncthreads();

    const int cnt = hist[t];
    for (int off = 1; off < 512; off <<= 1) {
        const int v = (t >= off) ? hist[t - off] : 0;
        __syncthreads();
        hist[t] += v;
        __syncthreads();
    }
    excl[t] = hist[t] - cnt;
    __syncthreads();
    if (t <= NBUCKET) offs[c * OFFS_W + t] = base + excl[t];   // excl[NBUCKET]==n

#pragma unroll
    for (int k = 0; k < CHUNK / 512; ++k) {
        const int i = t + k * 512;
        if (i < n) {
            const int pos = excl[ed[k] >> BSHIFT] + rk[k];
            ssrc[pos] = es[k];
            sdst[pos] = ed[k];
        }
    }
    __syncthreads();

    for (int i = t; i < n; i += 512)
        src_out[base + i] = ssrc[i];
    for (int i = t * 4; i < n; i += 2048) {
        const uint32 p = (uint32)(sdst[i] & 255)
                       | ((uint32)(sdst[i + 1] & 255) << 8)
                       | ((uint32)(sdst[i + 2] & 255) << 16)
                       | ((uint32)(sdst[i + 3] & 255) << 24);
        *(uint32*)&dst8[base + i] = p;
    }
}

// ---------------------------------------------------------------------------
// L2: blocks [0,391)      : per-bucket CSR finalize (latency-bound)
//     blocks [391,391+782): h = x @ W via MFMA (BW-bound, 8 waves x 16 rows)
// The two jobs are independent (join only at agg); CSR blocks are placed at
// low blockIdx so they start first, and the BW-bound GEMM streams around
// them -> L2 duration ~= max(gemm, csr) instead of the former sum.
// ---------------------------------------------------------------------------
__global__ __launch_bounds__(512) void k_mid(const float* __restrict__ x,
                                             const ushort16* __restrict__ Wt,
                                             ushort16* __restrict__ hb,
                                             const int* __restrict__ offs,
                                             const int* __restrict__ src_tmp,
                                             const unsigned char* __restrict__ dst8,
                                             int* __restrict__ srcs,
                                             int* __restrict__ row_ptr,
                                             int* __restrict__ row_end,
                                             float* __restrict__ dis) {
    __shared__ int hist[256];
    __shared__ int nxt[256];
    __shared__ int segb[NCHUNK];
    __shared__ int pre[NCHUNK + 1];
    __shared__ int sc[256];
    __shared__ int ssrc[CAP];       // 18.75 KB staging
    __shared__ int sb;

    if (blockIdx.x >= NBUCKET) {    // ---- gemm: 128 rows per block ----
        const int t    = threadIdx.x;
        const int lane = t & 63;
        const int wv   = t >> 6;                              // 0..7
        const int m15  = lane & 15;
        const int quad = lane >> 4;
        const int base = (blockIdx.x - NBUCKET) * 128 + wv * 16;
        const int arow = min(base + m15, N_NODES - 1);        // clamp tail

        const float* xr = &x[(size_t)arow * N_FEAT + quad * 8];
        float4 xa[4][2];
#pragma unroll
        for (int kc = 0; kc < 4; ++kc) {
            xa[kc][0] = *(const float4*)&xr[kc * 32];
            xa[kc][1] = *(const float4*)&xr[kc * 32 + 4];
        }

        Frag8 bf[4][4];
#pragma unroll
        for (int nt = 0; nt < 4; ++nt) {
            const ushort16* wr = &Wt[(nt * 16 + m15) * N_FEAT + quad * 8];
#pragma unroll
            for (int kc = 0; kc < 4; ++kc)
                bf[nt][kc].q = *(const uint4*)&wr[kc * 32];
        }

        Frag8 af[4];
#pragma unroll
        for (int kc = 0; kc < 4; ++kc) {
            const float* f = (const float*)&xa[kc][0];
#pragma unroll
            for (int j = 0; j < 8; ++j) af[kc].s[j] = f2bf(f[j]);
        }

        f32x4 acc[4];
#pragma unroll
        for (int nt = 0; nt < 4; ++nt) acc[nt] = (f32x4){0.f, 0.f, 0.f, 0.f};

#pragma unroll
        for (int kc = 0; kc < 4; ++kc)
#pragma unroll
            for (int nt = 0; nt < 4; ++nt)
                acc[nt] = __builtin_amdgcn_mfma_f32_16x16x32_bf16(af[kc].v, bf[nt][kc].v,
                                                                  acc[nt], 0, 0, 0);

#pragma unroll
        for (int r = 0; r < 4; ++r) {
            const int orow = base + quad * 4 + r;
            if (orow < N_NODES) {
#pragma unroll
                for (int nt = 0; nt < 4; ++nt)
                    hb[(size_t)orow * HIDDEN + nt * 16 + m15] = f2bf(acc[nt][r]);
            }
        }
        return;
    }

    // ---- bucket_csr ----
    const int b = blockIdx.x;
    const int lo = b << BSHIFT;
    const int t = threadIdx.x;

    if (t < 256) hist[t] = 0;
    if (t == 0) sb = 0;
    __syncthreads();

    int len = 0;
    if (t < NCHUNK) {
        const int s0 = offs[t * OFFS_W + b];
        const int s1 = offs[t * OFFS_W + b + 1];
        segb[t] = s0;
        len = s1 - s0;
        atomicAdd(&sb, s0 - t * CHUNK);     // closed-form bucket_start
    }
    if (t < 256) sc[t] = (t < NCHUNK) ? len : 0;
    __syncthreads();
    for (int off = 1; off < 256; off <<= 1) {
        int v = 0;
        if (t < 256 && t >= off) v = sc[t - off];
        __syncthreads();
        if (t < 256) sc[t] += v;
        __syncthreads();
    }
    if (t == 0) pre[0] = 0;
    if (t < NCHUNK) pre[t + 1] = sc[t];
    __syncthreads();

    const int total  = pre[NCHUNK];
    const int bstart = sb;
    const bool fits  = (total <= CAP);      // block-uniform

    int es[(CAP + 511) / 512], ed[(CAP + 511) / 512], rk[(CAP + 511) / 512];
    int ne = 0;
    if (fits) {
        for (int e = t; e < total; e += 512) {
            int l2 = 0, h2 = NCHUNK;
            while (h2 - l2 > 1) { const int mid = (l2 + h2) >> 1;
                                  if (pre[mid] <= e) l2 = mid; else h2 = mid; }
            const int gidx = segb[l2] + (e - pre[l2]);
            const int d = dst8[gidx];
            const int s = src_tmp[gidx];
            es[ne] = s; ed[ne] = d;
            rk[ne] = atomicAdd(&hist[d], 1);
            ++ne;
        }
    } else {                                 // fallback: count pass (rare)
        const int lane = t & 63, wv = t >> 6;
        for (int c = wv; c < NCHUNK; c += 8)
            for (int i = segb[c] + lane; i < segb[c] + (pre[c + 1] - pre[c]); i += 64)
                atomicAdd(&hist[dst8[i]], 1);
    }
    __syncthreads();

    const int cnt = (t < 256) ? hist[t] : 0;
    for (int off = 1; off < 256; off <<= 1) {
        int v = 0;
        if (t < 256 && t >= off) v = hist[t - off];
        __syncthreads();
        if (t < 256) hist[t] += v;
        __syncthreads();
    }
    if (t < 256) {
        const int excl = hist[t] - cnt;
        nxt[t] = excl;
        const int node = lo + t;
        if (node < N_NODES) {
            row_ptr[node] = bstart + excl;
            row_end[node] = bstart + excl + cnt;
            dis[node]     = rsqrtf((float)cnt + 1.0f);
        }
    }
    __syncthreads();

    if (fits) {
        for (int k = 0; k < ne; ++k)
            ssrc[nxt[ed[k]] + rk[k]] = es[k];   // LDS scatter
        __syncthreads();
        for (int i = t; i < total; i += 512)    // coalesced writeout
            srcs[bstart + i] = ssrc[i];
    } else {
        const int lane = t & 63, wv = t >> 6;
        for (int c = wv; c < NCHUNK; c += 8)
            for (int i = segb[c] + lane; i < segb[c] + (pre[c + 1] - pre[c]); i += 64) {
                const int d = dst8[i];
                const int pos = atomicAdd(&nxt[d], 1);
                srcs[bstart + pos] = src_tmp[i];
            }
    }
}

// ---------------------------------------------------------------------------
// L3: gather-aggregate, 8 nodes per wave, branchless inner loop; the last
// block to finish runs the tiny MLP inline (device-scope counter handshake,
// agent-scope atomic loads of u to bypass stale per-XCD L2 lines).
// ---------------------------------------------------------------------------
__global__ __launch_bounds__(256) void agg_kernel(const int* __restrict__ row_ptr,
                                                  const int* __restrict__ row_end,
                                                  const int* __restrict__ srcs,
                                                  const ushort16* __restrict__ hb,
                                                  const float* __restrict__ dis,
                                                  const float* __restrict__ bias,
                                                  const int* __restrict__ batch,
                                                  float* __restrict__ u,
                                                  const float* __restrict__ W1,
                                                  const float* __restrict__ b1,
                                                  const float* __restrict__ W2,
                                                  const float* __restrict__ b2,
                                                  float* __restrict__ out,
                                                  int* __restrict__ done) {
    __shared__ float sp[32][HIDDEN + 1];   // pad 65: write banks differ per g
    __shared__ int gbs[32];
    __shared__ int amLast;
    __shared__ float W1s[HIDDEN * 16];
    __shared__ float W2s[16];
    __shared__ float b1s[16];
    const int t = threadIdx.x;
    const int lane = t & 63;
    const int wv = t >> 6;
    const int g = lane >> 3;
    const int k = lane & 7;
    const int kb = lane & 56;              // g*8, shfl source base
    const int base = blockIdx.x * 32;
    const int node = base + wv * 8 + g;    // N_NODES = 32*3125 exactly
    const int beg = row_ptr[node];
    const int end = row_end[node];
    const int deg = end - beg;
    const float dn = dis[node];

    int dmax = deg;
    dmax = max(dmax, __shfl_xor(dmax, 8));
    dmax = max(dmax, __shfl_xor(dmax, 16));
    dmax = max(dmax, __shfl_xor(dmax, 32));

    float acc[8];
#pragma unroll
    for (int j = 0; j < 8; ++j) acc[j] = 0.f;

    for (int i0 = 0; i0 < dmax; i0 += 8) {
        int idx = beg + i0 + k;
        idx = min(idx, end - 1);
        idx = max(idx, 0);
        const int s8 = srcs[idx];
        const float w8 = dis[s8] * dn;

        int   si[8];
        float wi[8];
#pragma unroll
        for (int j = 0; j < 8; ++j) {
            si[j] = __shfl(s8, kb | j);
            const float w = __shfl(w8, kb | j);
            wi[j] = (i0 + j < deg) ? w : 0.f;
        }
        uint4 v[8];
#pragma unroll
        for (int j = 0; j < 8; ++j)
            v[j] = *(const uint4*)&hb[(size_t)si[j] * HIDDEN + k * 8];
#pragma unroll
        for (int j = 0; j < 8; ++j) {
            acc[0] = fmaf(__uint_as_float(v[j].x << 16),         wi[j], acc[0]);
            acc[1] = fmaf(__uint_as_float(v[j].x & 0xffff0000u), wi[j], acc[1]);
            acc[2] = fmaf(__uint_as_float(v[j].y << 16),         wi[j], acc[2]);
            acc[3] = fmaf(__uint_as_float(v[j].y & 0xffff0000u), wi[j], acc[3]);
            acc[4] = fmaf(__uint_as_float(v[j].z << 16),         wi[j], acc[4]);
            acc[5] = fmaf(__uint_as_float(v[j].z & 0xffff0000u), wi[j], acc[5]);
            acc[6] = fmaf(__uint_as_float(v[j].w << 16),         wi[j], acc[6]);
            acc[7] = fmaf(__uint_as_float(v[j].w & 0xffff0000u), wi[j], acc[7]);
        }
    }

    {
        const uint4 hv = *(const uint4*)&hb[(size_t)node * HIDDEN + k * 8];
        const float d2 = dn * dn;
        const float4 b0 = *(const float4*)&bias[k * 8];
        const float4 b1v = *(const float4*)&bias[k * 8 + 4];
        float4 r0, r1;
        r0.x = fmaxf(fmaf(__uint_as_float(hv.x << 16),         d2, acc[0]) + b0.x, 0.f);
        r0.y = fmaxf(fmaf(__uint_as_float(hv.x & 0xffff0000u), d2, acc[1]) + b0.y, 0.f);
        r0.z = fmaxf(fmaf(__uint_as_float(hv.y << 16),         d2, acc[2]) + b0.z, 0.f);
        r0.w = fmaxf(fmaf(__uint_as_float(hv.y & 0xffff0000u), d2, acc[3]) + b0.w, 0.f);
        r1.x = fmaxf(fmaf(__uint_as_float(hv.z << 16),         d2, acc[4]) + b1v.x, 0.f);
        r1.y = fmaxf(fmaf(__uint_as_float(hv.z & 0xffff0000u), d2, acc[5]) + b1v.y, 0.f);
        r1.z = fmaxf(fmaf(__uint_as_float(hv.w << 16),         d2, acc[6]) + b1v.z, 0.f);
        r1.w = fmaxf(fmaf(__uint_as_float(hv.w & 0xffff0000u), d2, acc[7]) + b1v.w, 0.f);
        *(float4*)&sp[wv * 8 + g][k * 8]     = r0;
        *(float4*)&sp[wv * 8 + g][k * 8 + 4] = r1;
    }
    if (t < 32) gbs[t] = batch[base + t];
    __syncthreads();

    if (t < 64) {
        float a = sp[0][t];
        int cg = gbs[0];
        for (int r = 1; r < 32; ++r) {
            const int gr = gbs[r];
            const float vv = sp[r][t];
            if (gr == cg) a += vv;
            else { atomicAdd(&u[cg * HIDDEN + t], a); cg = gr; a = vv; }
        }
        atomicAdd(&u[cg * HIDDEN + t], a);
    }

    // ---- last-block-runs-MLP tail ----
    __syncthreads();
    if (t == 0) {
        __threadfence();                                   // release our adds
        amLast = (atomicAdd(done, 1) == (int)gridDim.x - 1) ? 1 : 0;
    }
    __syncthreads();
    if (!amLast) return;
    __threadfence();                                       // acquire all adds

    for (int i = t; i < HIDDEN * 16; i += 256) W1s[i] = W1[i];
    if (t < 16) { W2s[t] = W2[t]; b1s[t] = b1[t]; }
    __syncthreads();
    if (t < NUM_GRAPHS) {
        float uu[HIDDEN];
#pragma unroll
        for (int kk = 0; kk < HIDDEN; ++kk)
            uu[kk] = __hip_atomic_load(&u[t * HIDDEN + kk], __ATOMIC_RELAXED,
                                       __HIP_MEMORY_SCOPE_AGENT);
        float o = b2[0];
#pragma unroll
        for (int j = 0; j < 16; ++j) {
            float s = b1s[j];
#pragma unroll
            for (int kk = 0; kk < HIDDEN; ++kk) s = fmaf(uu[kk], W1s[kk * 16 + j], s);
            o = fmaf(fmaxf(s, 0.f), W2s[j], o);
        }
        out[t] = o;
    }
}

// ---------------------------------------------------------------------------
extern "C" void kernel_launch(void* const* d_in, const int* in_sizes, int n_in,
                              void* d_out, int out_size, void* d_ws, size_t ws_size,
                              hipStream_t stream) {
    const float* x  = (const float*)d_in[0];
    const float* W  = (const float*)d_in[1];
    const float* b  = (const float*)d_in[2];
    const float* W1 = (const float*)d_in[3];
    const float* b1 = (const float*)d_in[4];
    const float* W2 = (const float*)d_in[5];
    const float* b2 = (const float*)d_in[6];
    const int*   ei = (const int*)d_in[7];     // [2, E] flat
    const int* batch = (const int*)d_in[8];    // [N], sorted
    float* out = (float*)d_out;

    ushort16* hb       = (ushort16*)d_ws;
    int*      src_tmp  = (int*)(hb + (size_t)N_NODES * HIDDEN);
    unsigned char* dst8 = (unsigned char*)(src_tmp + N_EDGES);
    int*      srcs     = (int*)(dst8 + N_EDGES);      // E multiple of 16 -> aligned
    int*      offs     = srcs + N_EDGES;
    int*      row_ptr  = offs + NCHUNK * OFFS_W;
    int*      row_end  = row_ptr + N_NODES;
    float*    dis      = (float*)(row_end + N_NODES);
    float*    u        = dis + N_NODES;
    int*      done     = (int*)(u + NUM_GRAPHS * HIDDEN);
    ushort16* Wtg      = (ushort16*)(done + 4);       // 64x128 bf16, 16B-aligned

    // zero u (atomic accumulators) + done (last-block counter) in one memset
    hipMemsetAsync(u, 0, NUM_GRAPHS * HIDDEN * sizeof(float) + 16, stream);

    k_pre<<<WT_BLOCKS + NCHUNK, 512, 0, stream>>>(W, Wtg, ei, src_tmp, dst8, offs);
    k_mid<<<NBUCKET + GEMM_GRID, 512, 0, stream>>>(x, Wtg, hb, offs, src_tmp, dst8,
                                                   srcs, row_ptr, row_end, dis);
    agg_kernel<<<N_NODES / 32, 256, 0, stream>>>(row_ptr, row_end, srcs, hb, dis, b,
                                                 batch, u, W1, b1, W2, b2, out, done);
}

// Round 2
// 177.428 us; speedup vs baseline: 1.3511x; 1.3511x over previous
//
#include <hip/hip_runtime.h>

#define N_NODES   100000
#define N_FEAT    128
#define N_EDGES   1600000
#define HIDDEN    64
#define NUM_GRAPHS 64
#define CHUNK   8192
#define NCHUNK  ((N_EDGES + CHUNK - 1) / CHUNK)   // 196
#define BSHIFT  8
#define NBUCKET ((N_NODES + 255) >> 8)            // 391 buckets of 256 nodes
#define OFFS_W  (NBUCKET + 1)                     // 392 entries per chunk
#define CAP     4800                              // max bucket size (mean 4092 + 11 sigma)
#define WT_BLOCKS 4
#define GEMM_GRID ((N_NODES + 127) / 128)         // 782 blocks of 128 rows

typedef unsigned int  uint32;
typedef unsigned short ushort16;

typedef __attribute__((ext_vector_type(8))) __bf16 bf16x8;
typedef __attribute__((ext_vector_type(4))) float  f32x4;
union Frag8 { bf16x8 v; unsigned short s[8]; uint4 q; };

// fp32 -> bf16 round-to-nearest-even
static __device__ __forceinline__ unsigned short f2bf(float f) {
    uint32 u = __float_as_uint(f);
    u += 0x7fffu + ((u >> 16) & 1u);
    return (unsigned short)(u >> 16);
}

// ---------------------------------------------------------------------------
// L1: blocks [0,4)   : Wt[n][k] = bf16(W[k][n])   (independent of edges)
//     blocks [4,200) : partition edges into 391 dst-buckets per 8192-edge
//                      chunk via LDS; all global writes coalesced.
// ---------------------------------------------------------------------------
__global__ __launch_bounds__(512) void k_pre(const float* __restrict__ W,
                                             ushort16* __restrict__ Wt,
                                             const int* __restrict__ ei,
                                             int* __restrict__ src_out,
                                             unsigned char* __restrict__ dst8,
                                             int* __restrict__ offs) {
    __shared__ int hist[512];
    __shared__ int excl[512];
    __shared__ int ssrc[CHUNK];     // 32 KB
    __shared__ int sdst[CHUNK];     // 32 KB

    if (blockIdx.x < WT_BLOCKS) {   // ---- w_transpose: 128*64 = 8192 elems
        const int base = blockIdx.x * 2048 + threadIdx.x;
#pragma unroll
        for (int j = 0; j < 4; ++j) {
            const int idx = base + j * 512;
            const int k = idx >> 6, n = idx & 63;
            Wt[n * N_FEAT + k] = f2bf(W[idx]);
        }
        return;
    }

    // ---- partition ----
    const int c = blockIdx.x - WT_BLOCKS;
    const int base = c * CHUNK;
    const int n = min(CHUNK, N_EDGES - base);   // always a multiple of 4
    const int t = threadIdx.x;
    hist[t] = 0;
    __syncthreads();

    int es[CHUNK / 512], ed[CHUNK / 512], rk[CHUNK / 512];
#pragma unroll
    for (int k = 0; k < CHUNK / 512; ++k) {
        const int i = t + k * 512;
        if (i < n) {
            ed[k] = __builtin_nontemporal_load(&ei[N_EDGES + base + i]);
            es[k] = __builtin_nontemporal_load(&ei[base + i]);
            rk[k] = atomicAdd(&hist[ed[k] >> BSHIFT], 1);
        }
    }
    __syncthreads();

    const int cnt = hist[t];
    for (int off = 1; off < 512; off <<= 1) {
        const int v = (t >= off) ? hist[t - off] : 0;
        __syncthreads();
        hist[t] += v;
        __syncthreads();
    }
    excl[t] = hist[t] - cnt;
    __syncthreads();
    if (t <= NBUCKET) offs[c * OFFS_W + t] = base + excl[t];   // excl[NBUCKET]==n

#pragma unroll
    for (int k = 0; k < CHUNK / 512; ++k) {
        const int i = t + k * 512;
        if (i < n) {
            const int pos = excl[ed[k] >> BSHIFT] + rk[k];
            ssrc[pos] = es[k];
            sdst[pos] = ed[k];
        }
    }
    __syncthreads();

    for (int i = t; i < n; i += 512)
        src_out[base + i] = ssrc[i];
    for (int i = t * 4; i < n; i += 2048) {
        const uint32 p = (uint32)(sdst[i] & 255)
                       | ((uint32)(sdst[i + 1] & 255) << 8)
                       | ((uint32)(sdst[i + 2] & 255) << 16)
                       | ((uint32)(sdst[i + 3] & 255) << 24);
        *(uint32*)&dst8[base + i] = p;
    }
}

// ---------------------------------------------------------------------------
// L2: blocks [0,391)      : per-bucket CSR finalize (latency-bound)
//     blocks [391,391+782): h = x @ W via MFMA (BW-bound, 8 waves x 16 rows)
// CSR blocks at low blockIdx start first; the BW-bound GEMM streams around
// them -> L2 duration ~= max(gemm, csr) instead of the former sum.
// ---------------------------------------------------------------------------
__global__ __launch_bounds__(512) void k_mid(const float* __restrict__ x,
                                             const ushort16* __restrict__ Wt,
                                             ushort16* __restrict__ hb,
                                             const int* __restrict__ offs,
                                             const int* __restrict__ src_tmp,
                                             const unsigned char* __restrict__ dst8,
                                             int* __restrict__ srcs,
                                             int* __restrict__ row_ptr,
                                             int* __restrict__ row_end,
                                             float* __restrict__ dis) {
    __shared__ int hist[256];
    __shared__ int nxt[256];
    __shared__ int segb[NCHUNK];
    __shared__ int pre[NCHUNK + 1];
    __shared__ int sc[256];
    __shared__ int ssrc[CAP];       // 18.75 KB staging
    __shared__ int sb;

    if (blockIdx.x >= NBUCKET) {    // ---- gemm: 128 rows per block ----
        const int t    = threadIdx.x;
        const int lane = t & 63;
        const int wv   = t >> 6;                              // 0..7
        const int m15  = lane & 15;
        const int quad = lane >> 4;
        const int base = (blockIdx.x - NBUCKET) * 128 + wv * 16;
        const int arow = min(base + m15, N_NODES - 1);        // clamp tail

        const float* xr = &x[(size_t)arow * N_FEAT + quad * 8];
        float4 xa[4][2];
#pragma unroll
        for (int kc = 0; kc < 4; ++kc) {
            xa[kc][0] = *(const float4*)&xr[kc * 32];
            xa[kc][1] = *(const float4*)&xr[kc * 32 + 4];
        }

        Frag8 bf[4][4];
#pragma unroll
        for (int nt = 0; nt < 4; ++nt) {
            const ushort16* wr = &Wt[(nt * 16 + m15) * N_FEAT + quad * 8];
#pragma unroll
            for (int kc = 0; kc < 4; ++kc)
                bf[nt][kc].q = *(const uint4*)&wr[kc * 32];
        }

        Frag8 af[4];
#pragma unroll
        for (int kc = 0; kc < 4; ++kc) {
            const float* f = (const float*)&xa[kc][0];
#pragma unroll
            for (int j = 0; j < 8; ++j) af[kc].s[j] = f2bf(f[j]);
        }

        f32x4 acc[4];
#pragma unroll
        for (int nt = 0; nt < 4; ++nt) acc[nt] = (f32x4){0.f, 0.f, 0.f, 0.f};

#pragma unroll
        for (int kc = 0; kc < 4; ++kc)
#pragma unroll
            for (int nt = 0; nt < 4; ++nt)
                acc[nt] = __builtin_amdgcn_mfma_f32_16x16x32_bf16(af[kc].v, bf[nt][kc].v,
                                                                  acc[nt], 0, 0, 0);

#pragma unroll
        for (int r = 0; r < 4; ++r) {
            const int orow = base + quad * 4 + r;
            if (orow < N_NODES) {
#pragma unroll
                for (int nt = 0; nt < 4; ++nt)
                    hb[(size_t)orow * HIDDEN + nt * 16 + m15] = f2bf(acc[nt][r]);
            }
        }
        return;
    }

    // ---- bucket_csr ----
    const int b = blockIdx.x;
    const int lo = b << BSHIFT;
    const int t = threadIdx.x;

    if (t < 256) hist[t] = 0;
    if (t == 0) sb = 0;
    __syncthreads();

    int len = 0;
    if (t < NCHUNK) {
        const int s0 = offs[t * OFFS_W + b];
        const int s1 = offs[t * OFFS_W + b + 1];
        segb[t] = s0;
        len = s1 - s0;
        atomicAdd(&sb, s0 - t * CHUNK);     // closed-form bucket_start
    }
    if (t < 256) sc[t] = (t < NCHUNK) ? len : 0;
    __syncthreads();
    for (int off = 1; off < 256; off <<= 1) {
        int v = 0;
        if (t < 256 && t >= off) v = sc[t - off];
        __syncthreads();
        if (t < 256) sc[t] += v;
        __syncthreads();
    }
    if (t == 0) pre[0] = 0;
    if (t < NCHUNK) pre[t + 1] = sc[t];
    __syncthreads();

    const int total  = pre[NCHUNK];
    const int bstart = sb;
    const bool fits  = (total <= CAP);      // block-uniform

    int es[(CAP + 511) / 512], ed[(CAP + 511) / 512], rk[(CAP + 511) / 512];
    int ne = 0;
    if (fits) {
        for (int e = t; e < total; e += 512) {
            int l2 = 0, h2 = NCHUNK;
            while (h2 - l2 > 1) { const int mid = (l2 + h2) >> 1;
                                  if (pre[mid] <= e) l2 = mid; else h2 = mid; }
            const int gidx = segb[l2] + (e - pre[l2]);
            const int d = dst8[gidx];
            const int s = src_tmp[gidx];
            es[ne] = s; ed[ne] = d;
            rk[ne] = atomicAdd(&hist[d], 1);
            ++ne;
        }
    } else {                                 // fallback: count pass (rare)
        const int lane = t & 63, wv = t >> 6;
        for (int c = wv; c < NCHUNK; c += 8)
            for (int i = segb[c] + lane; i < segb[c] + (pre[c + 1] - pre[c]); i += 64)
                atomicAdd(&hist[dst8[i]], 1);
    }
    __syncthreads();

    const int cnt = (t < 256) ? hist[t] : 0;
    for (int off = 1; off < 256; off <<= 1) {
        int v = 0;
        if (t < 256 && t >= off) v = hist[t - off];
        __syncthreads();
        if (t < 256) hist[t] += v;
        __syncthreads();
    }
    if (t < 256) {
        const int excl = hist[t] - cnt;
        nxt[t] = excl;
        const int node = lo + t;
        if (node < N_NODES) {
            row_ptr[node] = bstart + excl;
            row_end[node] = bstart + excl + cnt;
            dis[node]     = rsqrtf((float)cnt + 1.0f);
        }
    }
    __syncthreads();

    if (fits) {
        for (int k = 0; k < ne; ++k)
            ssrc[nxt[ed[k]] + rk[k]] = es[k];   // LDS scatter
        __syncthreads();
        for (int i = t; i < total; i += 512)    // coalesced writeout
            srcs[bstart + i] = ssrc[i];
    } else {
        const int lane = t & 63, wv = t >> 6;
        for (int c = wv; c < NCHUNK; c += 8)
            for (int i = segb[c] + lane; i < segb[c] + (pre[c + 1] - pre[c]); i += 64) {
                const int d = dst8[i];
                const int pos = atomicAdd(&nxt[d], 1);
                srcs[bstart + pos] = src_tmp[i];
            }
    }
}

// ---------------------------------------------------------------------------
// K4: gather-aggregate, 8 nodes per wave, branchless inner loop.
// Reverted to the round-0 form: no MLP tail, no fences, no done counter —
// the tail inflated VGPR to 128 and its per-block __threadfence thrashed L2
// (agg 41 -> 104 us). Keeping it lean restores occupancy + cache locality.
// ---------------------------------------------------------------------------
__global__ __launch_bounds__(256) void agg_kernel(const int* __restrict__ row_ptr,
                                                  const int* __restrict__ row_end,
                                                  const int* __restrict__ srcs,
                                                  const ushort16* __restrict__ hb,
                                                  const float* __restrict__ dis,
                                                  const float* __restrict__ bias,
                                                  const int* __restrict__ batch,
                                                  float* __restrict__ u) {
    __shared__ float sp[32][HIDDEN + 1];   // pad 65: write banks differ per g
    __shared__ int gbs[32];
    const int t = threadIdx.x;
    const int lane = t & 63;
    const int wv = t >> 6;
    const int g = lane >> 3;
    const int k = lane & 7;
    const int kb = lane & 56;              // g*8, shfl source base
    const int base = blockIdx.x * 32;
    const int node = base + wv * 8 + g;    // N_NODES = 32*3125 exactly
    const int beg = row_ptr[node];
    const int end = row_end[node];
    const int deg = end - beg;
    const float dn = dis[node];

    int dmax = deg;
    dmax = max(dmax, __shfl_xor(dmax, 8));
    dmax = max(dmax, __shfl_xor(dmax, 16));
    dmax = max(dmax, __shfl_xor(dmax, 32));

    float acc[8];
#pragma unroll
    for (int j = 0; j < 8; ++j) acc[j] = 0.f;

    for (int i0 = 0; i0 < dmax; i0 += 8) {
        int idx = beg + i0 + k;
        idx = min(idx, end - 1);
        idx = max(idx, 0);
        const int s8 = srcs[idx];
        const float w8 = dis[s8] * dn;

        int   si[8];
        float wi[8];
#pragma unroll
        for (int j = 0; j < 8; ++j) {
            si[j] = __shfl(s8, kb | j);
            const float w = __shfl(w8, kb | j);
            wi[j] = (i0 + j < deg) ? w : 0.f;
        }
        uint4 v[8];
#pragma unroll
        for (int j = 0; j < 8; ++j)
            v[j] = *(const uint4*)&hb[(size_t)si[j] * HIDDEN + k * 8];
#pragma unroll
        for (int j = 0; j < 8; ++j) {
            acc[0] = fmaf(__uint_as_float(v[j].x << 16),         wi[j], acc[0]);
            acc[1] = fmaf(__uint_as_float(v[j].x & 0xffff0000u), wi[j], acc[1]);
            acc[2] = fmaf(__uint_as_float(v[j].y << 16),         wi[j], acc[2]);
            acc[3] = fmaf(__uint_as_float(v[j].y & 0xffff0000u), wi[j], acc[3]);
            acc[4] = fmaf(__uint_as_float(v[j].z << 16),         wi[j], acc[4]);
            acc[5] = fmaf(__uint_as_float(v[j].z & 0xffff0000u), wi[j], acc[5]);
            acc[6] = fmaf(__uint_as_float(v[j].w << 16),         wi[j], acc[6]);
            acc[7] = fmaf(__uint_as_float(v[j].w & 0xffff0000u), wi[j], acc[7]);
        }
    }

    {
        const uint4 hv = *(const uint4*)&hb[(size_t)node * HIDDEN + k * 8];
        const float d2 = dn * dn;
        const float4 b0 = *(const float4*)&bias[k * 8];
        const float4 b1 = *(const float4*)&bias[k * 8 + 4];
        float4 r0, r1;
        r0.x = fmaxf(fmaf(__uint_as_float(hv.x << 16),         d2, acc[0]) + b0.x, 0.f);
        r0.y = fmaxf(fmaf(__uint_as_float(hv.x & 0xffff0000u), d2, acc[1]) + b0.y, 0.f);
        r0.z = fmaxf(fmaf(__uint_as_float(hv.y << 16),         d2, acc[2]) + b0.z, 0.f);
        r0.w = fmaxf(fmaf(__uint_as_float(hv.y & 0xffff0000u), d2, acc[3]) + b0.w, 0.f);
        r1.x = fmaxf(fmaf(__uint_as_float(hv.z << 16),         d2, acc[4]) + b1.x, 0.f);
        r1.y = fmaxf(fmaf(__uint_as_float(hv.z & 0xffff0000u), d2, acc[5]) + b1.y, 0.f);
        r1.z = fmaxf(fmaf(__uint_as_float(hv.w << 16),         d2, acc[6]) + b1.z, 0.f);
        r1.w = fmaxf(fmaf(__uint_as_float(hv.w & 0xffff0000u), d2, acc[7]) + b1.w, 0.f);
        *(float4*)&sp[wv * 8 + g][k * 8]     = r0;
        *(float4*)&sp[wv * 8 + g][k * 8 + 4] = r1;
    }
    if (t < 32) gbs[t] = batch[base + t];
    __syncthreads();

    if (t < 64) {
        float a = sp[0][t];
        int cg = gbs[0];
        for (int r = 1; r < 32; ++r) {
            const int gr = gbs[r];
            const float vv = sp[r][t];
            if (gr == cg) a += vv;
            else { atomicAdd(&u[cg * HIDDEN + t], a); cg = gr; a = vv; }
        }
        atomicAdd(&u[cg * HIDDEN + t], a);
    }
}

// ---------------------------------------------------------------------------
// K5: out[g] = relu(u[g] @ W1 + b1) @ W2 + b2
// ---------------------------------------------------------------------------
__global__ __launch_bounds__(64) void mlp_kernel(const float* __restrict__ u,
                                                 const float* __restrict__ W1,
                                                 const float* __restrict__ b1,
                                                 const float* __restrict__ W2,
                                                 const float* __restrict__ b2,
                                                 float* __restrict__ out) {
    __shared__ float W1s[HIDDEN * 16];
    __shared__ float W2s[16];
    __shared__ float b1s[16];
    const int t = threadIdx.x;
    for (int i = t; i < HIDDEN * 16; i += 64) W1s[i] = W1[i];
    if (t < 16) { W2s[t] = W2[t]; b1s[t] = b1[t]; }
    __syncthreads();
    if (t < NUM_GRAPHS) {
        float uu[HIDDEN];
#pragma unroll
        for (int k = 0; k < HIDDEN; ++k) uu[k] = u[t * HIDDEN + k];
        float o = b2[0];
#pragma unroll
        for (int j = 0; j < 16; ++j) {
            float s = b1s[j];
#pragma unroll
            for (int k = 0; k < HIDDEN; ++k) s = fmaf(uu[k], W1s[k * 16 + j], s);
            o = fmaf(fmaxf(s, 0.f), W2s[j], o);
        }
        out[t] = o;
    }
}

// ---------------------------------------------------------------------------
extern "C" void kernel_launch(void* const* d_in, const int* in_sizes, int n_in,
                              void* d_out, int out_size, void* d_ws, size_t ws_size,
                              hipStream_t stream) {
    const float* x  = (const float*)d_in[0];
    const float* W  = (const float*)d_in[1];
    const float* b  = (const float*)d_in[2];
    const float* W1 = (const float*)d_in[3];
    const float* b1 = (const float*)d_in[4];
    const float* W2 = (const float*)d_in[5];
    const float* b2 = (const float*)d_in[6];
    const int*   ei = (const int*)d_in[7];     // [2, E] flat
    const int* batch = (const int*)d_in[8];    // [N], sorted
    float* out = (float*)d_out;

    ushort16* hb       = (ushort16*)d_ws;
    int*      src_tmp  = (int*)(hb + (size_t)N_NODES * HIDDEN);
    unsigned char* dst8 = (unsigned char*)(src_tmp + N_EDGES);
    int*      srcs     = (int*)(dst8 + N_EDGES);      // E multiple of 16 -> aligned
    int*      offs     = srcs + N_EDGES;
    int*      row_ptr  = offs + NCHUNK * OFFS_W;
    int*      row_end  = row_ptr + N_NODES;
    float*    dis      = (float*)(row_end + N_NODES);
    float*    u        = dis + N_NODES;
    ushort16* Wtg      = (ushort16*)(u + NUM_GRAPHS * HIDDEN);   // 64x128 bf16

    hipMemsetAsync(u, 0, NUM_GRAPHS * HIDDEN * sizeof(float), stream);

    k_pre<<<WT_BLOCKS + NCHUNK, 512, 0, stream>>>(W, Wtg, ei, src_tmp, dst8, offs);
    k_mid<<<NBUCKET + GEMM_GRID, 512, 0, stream>>>(x, Wtg, hb, offs, src_tmp, dst8,
                                                   srcs, row_ptr, row_end, dis);
    agg_kernel<<<N_NODES / 32, 256, 0, stream>>>(row_ptr, row_end, srcs, hb, dis, b, batch, u);
    mlp_kernel<<<1, 64, 0, stream>>>(u, W1, b1, W2, b2, out);
}

// Round 3
// 175.438 us; speedup vs baseline: 1.3665x; 1.0113x over previous
//
#include <hip/hip_runtime.h>

#define N_NODES   100000
#define N_FEAT    128
#define N_EDGES   1600000
#define HIDDEN    64
#define NUM_GRAPHS 64
#define CHUNK   4096
#define NCHUNK  ((N_EDGES + CHUNK - 1) / CHUNK)   // 391 chunks of 4096 edges
#define BSHIFT  8
#define NBUCKET ((N_NODES + 255) >> 8)            // 391 buckets of 256 nodes
#define OFFS_W  (NBUCKET + 1)                     // 392 entries per chunk
#define CAP     4800                              // max bucket size (mean 4092 + 11 sigma)
#define WT_BLOCKS 4
#define GEMM_GRID ((N_NODES + 127) / 128)         // 782 blocks of 128 rows

typedef unsigned int  uint32;
typedef unsigned short ushort16;

typedef __attribute__((ext_vector_type(8))) __bf16 bf16x8;
typedef __attribute__((ext_vector_type(4))) float  f32x4;
union Frag8 { bf16x8 v; unsigned short s[8]; uint4 q; };

// fp32 -> bf16 round-to-nearest-even
static __device__ __forceinline__ unsigned short f2bf(float f) {
    uint32 u = __float_as_uint(f);
    u += 0x7fffu + ((u >> 16) & 1u);
    return (unsigned short)(u >> 16);
}

// ---------------------------------------------------------------------------
// L1: blocks [0,4)   : Wt[n][k] = bf16(W[k][n])   (independent of edges)
//     blocks [4,395) : partition edges into 391 dst-buckets per 4096-edge
//                      chunk via LDS. CHUNK=4096 (was 8192): 36 KB LDS ->
//                      4 blocks/CU and 391 blocks (1.5/CU, was 0.77/CU).
// ---------------------------------------------------------------------------
__global__ __launch_bounds__(512) void k_pre(const float* __restrict__ W,
                                             ushort16* __restrict__ Wt,
                                             const int* __restrict__ ei,
                                             int* __restrict__ src_out,
                                             unsigned char* __restrict__ dst8,
                                             int* __restrict__ offs) {
    __shared__ int hist[512];
    __shared__ int excl[512];
    __shared__ int ssrc[CHUNK];     // 16 KB
    __shared__ int sdst[CHUNK];     // 16 KB

    if (blockIdx.x < WT_BLOCKS) {   // ---- w_transpose: 128*64 = 8192 elems
        const int base = blockIdx.x * 2048 + threadIdx.x;
#pragma unroll
        for (int j = 0; j < 4; ++j) {
            const int idx = base + j * 512;
            const int k = idx >> 6, n = idx & 63;
            Wt[n * N_FEAT + k] = f2bf(W[idx]);
        }
        return;
    }

    // ---- partition ----
    const int c = blockIdx.x - WT_BLOCKS;
    const int base = c * CHUNK;
    const int n = min(CHUNK, N_EDGES - base);   // always a multiple of 4
    const int t = threadIdx.x;
    hist[t] = 0;
    __syncthreads();

    int es[CHUNK / 512], ed[CHUNK / 512], rk[CHUNK / 512];
#pragma unroll
    for (int k = 0; k < CHUNK / 512; ++k) {
        const int i = t + k * 512;
        if (i < n) {
            ed[k] = __builtin_nontemporal_load(&ei[N_EDGES + base + i]);
            es[k] = __builtin_nontemporal_load(&ei[base + i]);
            rk[k] = atomicAdd(&hist[ed[k] >> BSHIFT], 1);
        }
    }
    __syncthreads();

    const int cnt = hist[t];
    for (int off = 1; off < 512; off <<= 1) {
        const int v = (t >= off) ? hist[t - off] : 0;
        __syncthreads();
        hist[t] += v;
        __syncthreads();
    }
    excl[t] = hist[t] - cnt;
    __syncthreads();
    if (t <= NBUCKET) offs[c * OFFS_W + t] = base + excl[t];   // excl[NBUCKET]==n

#pragma unroll
    for (int k = 0; k < CHUNK / 512; ++k) {
        const int i = t + k * 512;
        if (i < n) {
            const int pos = excl[ed[k] >> BSHIFT] + rk[k];
            ssrc[pos] = es[k];
            sdst[pos] = ed[k];
        }
    }
    __syncthreads();

    for (int i = t; i < n; i += 512)
        src_out[base + i] = ssrc[i];
    for (int i = t * 4; i < n; i += 2048) {
        const uint32 p = (uint32)(sdst[i] & 255)
                       | ((uint32)(sdst[i + 1] & 255) << 8)
                       | ((uint32)(sdst[i + 2] & 255) << 16)
                       | ((uint32)(sdst[i + 3] & 255) << 24);
        *(uint32*)&dst8[base + i] = p;
    }
}

// ---------------------------------------------------------------------------
// L2: blocks [0,391)      : per-bucket CSR finalize (latency-bound)
//     blocks [391,391+782): h = x @ W via MFMA (BW-bound, 8 waves x 16 rows)
// CSR blocks at low blockIdx start first; the BW-bound GEMM streams around
// them -> L2 duration ~= max(gemm, csr) instead of the former sum.
// ---------------------------------------------------------------------------
__global__ __launch_bounds__(512) void k_mid(const float* __restrict__ x,
                                             const ushort16* __restrict__ Wt,
                                             ushort16* __restrict__ hb,
                                             const int* __restrict__ offs,
                                             const int* __restrict__ src_tmp,
                                             const unsigned char* __restrict__ dst8,
                                             int* __restrict__ srcs,
                                             int* __restrict__ row_ptr,
                                             int* __restrict__ row_end,
                                             float* __restrict__ dis) {
    __shared__ int hist[256];
    __shared__ int nxt[256];
    __shared__ int segb[NCHUNK];
    __shared__ int pre[NCHUNK + 1];
    __shared__ int sc[512];
    __shared__ int ssrc[CAP];       // 18.75 KB staging
    __shared__ int sb;

    if (blockIdx.x >= NBUCKET) {    // ---- gemm: 128 rows per block ----
        const int t    = threadIdx.x;
        const int lane = t & 63;
        const int wv   = t >> 6;                              // 0..7
        const int m15  = lane & 15;
        const int quad = lane >> 4;
        const int base = (blockIdx.x - NBUCKET) * 128 + wv * 16;
        const int arow = min(base + m15, N_NODES - 1);        // clamp tail

        const float* xr = &x[(size_t)arow * N_FEAT + quad * 8];
        float4 xa[4][2];
#pragma unroll
        for (int kc = 0; kc < 4; ++kc) {
            xa[kc][0] = *(const float4*)&xr[kc * 32];
            xa[kc][1] = *(const float4*)&xr[kc * 32 + 4];
        }

        Frag8 bf[4][4];
#pragma unroll
        for (int nt = 0; nt < 4; ++nt) {
            const ushort16* wr = &Wt[(nt * 16 + m15) * N_FEAT + quad * 8];
#pragma unroll
            for (int kc = 0; kc < 4; ++kc)
                bf[nt][kc].q = *(const uint4*)&wr[kc * 32];
        }

        Frag8 af[4];
#pragma unroll
        for (int kc = 0; kc < 4; ++kc) {
            const float* f = (const float*)&xa[kc][0];
#pragma unroll
            for (int j = 0; j < 8; ++j) af[kc].s[j] = f2bf(f[j]);
        }

        f32x4 acc[4];
#pragma unroll
        for (int nt = 0; nt < 4; ++nt) acc[nt] = (f32x4){0.f, 0.f, 0.f, 0.f};

#pragma unroll
        for (int kc = 0; kc < 4; ++kc)
#pragma unroll
            for (int nt = 0; nt < 4; ++nt)
                acc[nt] = __builtin_amdgcn_mfma_f32_16x16x32_bf16(af[kc].v, bf[nt][kc].v,
                                                                  acc[nt], 0, 0, 0);

#pragma unroll
        for (int r = 0; r < 4; ++r) {
            const int orow = base + quad * 4 + r;
            if (orow < N_NODES) {
#pragma unroll
                for (int nt = 0; nt < 4; ++nt)
                    hb[(size_t)orow * HIDDEN + nt * 16 + m15] = f2bf(acc[nt][r]);
            }
        }
        return;
    }

    // ---- bucket_csr ----
    const int b = blockIdx.x;
    const int lo = b << BSHIFT;
    const int t = threadIdx.x;

    if (t < 256) hist[t] = 0;
    if (t == 0) sb = 0;
    __syncthreads();

    int len = 0;
    if (t < NCHUNK) {
        const int s0 = offs[t * OFFS_W + b];
        const int s1 = offs[t * OFFS_W + b + 1];
        segb[t] = s0;
        len = s1 - s0;
        atomicAdd(&sb, s0 - t * CHUNK);     // closed-form bucket_start
    }
    sc[t] = len;                             // 512-wide scan (NCHUNK=391>256)
    __syncthreads();
    for (int off = 1; off < 512; off <<= 1) {
        const int v = (t >= off) ? sc[t - off] : 0;
        __syncthreads();
        sc[t] += v;
        __syncthreads();
    }
    if (t == 0) pre[0] = 0;
    if (t < NCHUNK) pre[t + 1] = sc[t];
    __syncthreads();

    const int total  = pre[NCHUNK];
    const int bstart = sb;
    const bool fits  = (total <= CAP);      // block-uniform

    int es[(CAP + 511) / 512], ed[(CAP + 511) / 512], rk[(CAP + 511) / 512];
    int ne = 0;
    if (fits) {
        for (int e = t; e < total; e += 512) {
            int l2 = 0, h2 = NCHUNK;
            while (h2 - l2 > 1) { const int mid = (l2 + h2) >> 1;
                                  if (pre[mid] <= e) l2 = mid; else h2 = mid; }
            const int gidx = segb[l2] + (e - pre[l2]);
            const int d = dst8[gidx];
            const int s = src_tmp[gidx];
            es[ne] = s; ed[ne] = d;
            rk[ne] = atomicAdd(&hist[d], 1);
            ++ne;
        }
    } else {                                 // fallback: count pass (rare)
        const int lane = t & 63, wv = t >> 6;
        for (int c = wv; c < NCHUNK; c += 8)
            for (int i = segb[c] + lane; i < segb[c] + (pre[c + 1] - pre[c]); i += 64)
                atomicAdd(&hist[dst8[i]], 1);
    }
    __syncthreads();

    const int cnt = (t < 256) ? hist[t] : 0;
    for (int off = 1; off < 256; off <<= 1) {
        int v = 0;
        if (t < 256 && t >= off) v = hist[t - off];
        __syncthreads();
        if (t < 256) hist[t] += v;
        __syncthreads();
    }
    if (t < 256) {
        const int excl = hist[t] - cnt;
        nxt[t] = excl;
        const int node = lo + t;
        if (node < N_NODES) {
            row_ptr[node] = bstart + excl;
            row_end[node] = bstart + excl + cnt;
            dis[node]     = rsqrtf((float)cnt + 1.0f);
        }
    }
    __syncthreads();

    if (fits) {
        for (int k = 0; k < ne; ++k)
            ssrc[nxt[ed[k]] + rk[k]] = es[k];   // LDS scatter
        __syncthreads();
        for (int i = t; i < total; i += 512)    // coalesced writeout
            srcs[bstart + i] = ssrc[i];
    } else {
        const int lane = t & 63, wv = t >> 6;
        for (int c = wv; c < NCHUNK; c += 8)
            for (int i = segb[c] + lane; i < segb[c] + (pre[c + 1] - pre[c]); i += 64) {
                const int d = dst8[i];
                const int pos = atomicAdd(&nxt[d], 1);
                srcs[bstart + pos] = src_tmp[i];
            }
    }
}

// ---------------------------------------------------------------------------
// K3.5: hb[node] *= dis[node]  (in place, bf16). dn = dis[dst] factors out of
// the whole aggregation row-sum, so pre-scaling by dis[src] here removes the
// dependent dis[src] random gather (one full latency level) AND the weight
// shuffle from agg's inner loop. 25.6 MB streaming ≈ 5 us.
// ---------------------------------------------------------------------------
__global__ __launch_bounds__(256) void k_scale(ushort16* __restrict__ hb,
                                               const float* __restrict__ dis) {
    const int i = blockIdx.x * 256 + threadIdx.x;     // 800000 = 3125*256 exactly
    const float dn = dis[i >> 3];
    uint4 v = *(const uint4*)&hb[(size_t)i * 8];
    uint4 r;
    r.x = (uint32)f2bf(__uint_as_float(v.x << 16) * dn)
        | ((uint32)f2bf(__uint_as_float(v.x & 0xffff0000u) * dn) << 16);
    r.y = (uint32)f2bf(__uint_as_float(v.y << 16) * dn)
        | ((uint32)f2bf(__uint_as_float(v.y & 0xffff0000u) * dn) << 16);
    r.z = (uint32)f2bf(__uint_as_float(v.z << 16) * dn)
        | ((uint32)f2bf(__uint_as_float(v.z & 0xffff0000u) * dn) << 16);
    r.w = (uint32)f2bf(__uint_as_float(v.w << 16) * dn)
        | ((uint32)f2bf(__uint_as_float(v.w & 0xffff0000u) * dn) << 16);
    *(uint4*)&hb[(size_t)i * 8] = r;
}

// ---------------------------------------------------------------------------
// K4: gather-aggregate over PRE-SCALED hs = h*dis. Per 8-lane group loop to
// its OWN node degree (shfl sources stay in-group -> exec-mask safe): removes
// the dmax padding (~33% of gather traffic). Next batch's srcs prefetched so
// the 2-level chain (srcs -> hb) pipelines. result = relu(dn*(sum+self)+b).
// ---------------------------------------------------------------------------
__global__ __launch_bounds__(256) void agg_kernel(const int* __restrict__ row_ptr,
                                                  const int* __restrict__ row_end,
                                                  const int* __restrict__ srcs,
                                                  const ushort16* __restrict__ hb,
                                                  const float* __restrict__ dis,
                                                  const float* __restrict__ bias,
                                                  const int* __restrict__ batch,
                                                  float* __restrict__ u) {
    __shared__ float sp[32][HIDDEN + 1];   // pad 65: write banks differ per g
    __shared__ int gbs[32];
    const int t = threadIdx.x;
    const int lane = t & 63;
    const int wv = t >> 6;
    const int g = lane >> 3;
    const int k = lane & 7;
    const int kb = lane & 56;              // g*8, shfl source base
    const int base = blockIdx.x * 32;
    const int node = base + wv * 8 + g;    // N_NODES = 32*3125 exactly
    const int beg = row_ptr[node];
    const int end = row_end[node];
    const int deg = end - beg;
    const float dn = dis[node];

    float acc[8];
#pragma unroll
    for (int j = 0; j < 8; ++j) acc[j] = 0.f;

    int pidx = max(min(beg + k, end - 1), 0);
    int s8 = srcs[pidx];                   // prefetched batch 0

    for (int i0 = 0; i0 < deg; i0 += 8) {
        const int rem = deg - i0;
        const int cur = s8;
        if (i0 + 8 < deg)                  // group-uniform: prefetch batch i+1
            s8 = srcs[min(beg + i0 + 8 + k, end - 1)];

        int si[8];
#pragma unroll
        for (int j = 0; j < 8; ++j) si[j] = __shfl(cur, kb | j);
        uint4 v[8];
#pragma unroll
        for (int j = 0; j < 8; ++j)
            v[j] = *(const uint4*)&hb[(size_t)si[j] * HIDDEN + k * 8];
#pragma unroll
        for (int j = 0; j < 8; ++j) {
            const float m = (j < rem) ? 1.f : 0.f;
            acc[0] = fmaf(__uint_as_float(v[j].x << 16),         m, acc[0]);
            acc[1] = fmaf(__uint_as_float(v[j].x & 0xffff0000u), m, acc[1]);
            acc[2] = fmaf(__uint_as_float(v[j].y << 16),         m, acc[2]);
            acc[3] = fmaf(__uint_as_float(v[j].y & 0xffff0000u), m, acc[3]);
            acc[4] = fmaf(__uint_as_float(v[j].z << 16),         m, acc[4]);
            acc[5] = fmaf(__uint_as_float(v[j].z & 0xffff0000u), m, acc[5]);
            acc[6] = fmaf(__uint_as_float(v[j].w << 16),         m, acc[6]);
            acc[7] = fmaf(__uint_as_float(v[j].w & 0xffff0000u), m, acc[7]);
        }
    }

    {   // self-loop: hs[node]*dn = h[node]*dn^2; edges: dn * sum(hs[src])
        const uint4 hv = *(const uint4*)&hb[(size_t)node * HIDDEN + k * 8];
        const float4 b0 = *(const float4*)&bias[k * 8];
        const float4 b1 = *(const float4*)&bias[k * 8 + 4];
        float4 r0, r1;
        r0.x = fmaxf(fmaf(acc[0] + __uint_as_float(hv.x << 16),         dn, b0.x), 0.f);
        r0.y = fmaxf(fmaf(acc[1] + __uint_as_float(hv.x & 0xffff0000u), dn, b0.y), 0.f);
        r0.z = fmaxf(fmaf(acc[2] + __uint_as_float(hv.y << 16),         dn, b0.z), 0.f);
        r0.w = fmaxf(fmaf(acc[3] + __uint_as_float(hv.y & 0xffff0000u), dn, b0.w), 0.f);
        r1.x = fmaxf(fmaf(acc[4] + __uint_as_float(hv.z << 16),         dn, b1.x), 0.f);
        r1.y = fmaxf(fmaf(acc[5] + __uint_as_float(hv.z & 0xffff0000u), dn, b1.y), 0.f);
        r1.z = fmaxf(fmaf(acc[6] + __uint_as_float(hv.w << 16),         dn, b1.z), 0.f);
        r1.w = fmaxf(fmaf(acc[7] + __uint_as_float(hv.w & 0xffff0000u), dn, b1.w), 0.f);
        *(float4*)&sp[wv * 8 + g][k * 8]     = r0;
        *(float4*)&sp[wv * 8 + g][k * 8 + 4] = r1;
    }
    if (t < 32) gbs[t] = batch[base + t];
    __syncthreads();

    if (t < 64) {
        float a = sp[0][t];
        int cg = gbs[0];
        for (int r = 1; r < 32; ++r) {
            const int gr = gbs[r];
            const float vv = sp[r][t];
            if (gr == cg) a += vv;
            else { atomicAdd(&u[cg * HIDDEN + t], a); cg = gr; a = vv; }
        }
        atomicAdd(&u[cg * HIDDEN + t], a);
    }
}

// ---------------------------------------------------------------------------
// K5: out[g] = relu(u[g] @ W1 + b1) @ W2 + b2
// ---------------------------------------------------------------------------
__global__ __launch_bounds__(64) void mlp_kernel(const float* __restrict__ u,
                                                 const float* __restrict__ W1,
                                                 const float* __restrict__ b1,
                                                 const float* __restrict__ W2,
                                                 const float* __restrict__ b2,
                                                 float* __restrict__ out) {
    __shared__ float W1s[HIDDEN * 16];
    __shared__ float W2s[16];
    __shared__ float b1s[16];
    const int t = threadIdx.x;
    for (int i = t; i < HIDDEN * 16; i += 64) W1s[i] = W1[i];
    if (t < 16) { W2s[t] = W2[t]; b1s[t] = b1[t]; }
    __syncthreads();
    if (t < NUM_GRAPHS) {
        float uu[HIDDEN];
#pragma unroll
        for (int k = 0; k < HIDDEN; ++k) uu[k] = u[t * HIDDEN + k];
        float o = b2[0];
#pragma unroll
        for (int j = 0; j < 16; ++j) {
            float s = b1s[j];
#pragma unroll
            for (int k = 0; k < HIDDEN; ++k) s = fmaf(uu[k], W1s[k * 16 + j], s);
            o = fmaf(fmaxf(s, 0.f), W2s[j], o);
        }
        out[t] = o;
    }
}

// ---------------------------------------------------------------------------
extern "C" void kernel_launch(void* const* d_in, const int* in_sizes, int n_in,
                              void* d_out, int out_size, void* d_ws, size_t ws_size,
                              hipStream_t stream) {
    const float* x  = (const float*)d_in[0];
    const float* W  = (const float*)d_in[1];
    const float* b  = (const float*)d_in[2];
    const float* W1 = (const float*)d_in[3];
    const float* b1 = (const float*)d_in[4];
    const float* W2 = (const float*)d_in[5];
    const float* b2 = (const float*)d_in[6];
    const int*   ei = (const int*)d_in[7];     // [2, E] flat
    const int* batch = (const int*)d_in[8];    // [N], sorted
    float* out = (float*)d_out;

    ushort16* hb       = (ushort16*)d_ws;
    int*      src_tmp  = (int*)(hb + (size_t)N_NODES * HIDDEN);
    unsigned char* dst8 = (unsigned char*)(src_tmp + N_EDGES);
    int*      srcs     = (int*)(dst8 + N_EDGES);      // E multiple of 16 -> aligned
    int*      offs     = srcs + N_EDGES;
    int*      row_ptr  = offs + NCHUNK * OFFS_W;
    int*      row_end  = row_ptr + N_NODES;
    float*    dis      = (float*)(row_end + N_NODES);
    float*    u        = dis + N_NODES;
    ushort16* Wtg      = (ushort16*)(u + NUM_GRAPHS * HIDDEN);   // 64x128 bf16

    hipMemsetAsync(u, 0, NUM_GRAPHS * HIDDEN * sizeof(float), stream);

    k_pre<<<WT_BLOCKS + NCHUNK, 512, 0, stream>>>(W, Wtg, ei, src_tmp, dst8, offs);
    k_mid<<<NBUCKET + GEMM_GRID, 512, 0, stream>>>(x, Wtg, hb, offs, src_tmp, dst8,
                                                   srcs, row_ptr, row_end, dis);
    k_scale<<<3125, 256, 0, stream>>>(hb, dis);
    agg_kernel<<<N_NODES / 32, 256, 0, stream>>>(row_ptr, row_end, srcs, hb, dis, b, batch, u);
    mlp_kernel<<<1, 64, 0, stream>>>(u, W1, b1, W2, b2, out);
}